// Round 18
// baseline (78.463 us; speedup 1.0000x reference)
//
#include <hip/hip_runtime.h>
#include <hip/hip_bf16.h>

typedef unsigned short u16;
typedef unsigned int u32;
typedef __attribute__((ext_vector_type(8))) short bf16x8;
typedef __attribute__((ext_vector_type(4))) float f32x4;
typedef __attribute__((ext_vector_type(2))) float f32x2;
typedef __attribute__((ext_vector_type(4))) unsigned short u16x4;

#define NBLK 256   // 256 blocks x 512 rows = 131072 rows; 1 block/CU (LDS-capped)

// shared_exp = floor(log2(amax)) - 8 ; scale = 2^shared_exp (power of two)
__device__ __forceinline__ void block_scale(float amax, float& scale, float& inv_scale) {
    int be = (int)(__float_as_uint(amax) >> 23);   // biased exponent, amax >= 0
    be = be < 8 ? 8 : be;                          // tiny/zero blocks quantize to 0 anyway
    scale     = __uint_as_float((unsigned)(be - 8) << 23);   // 2^(be-135)
    inv_scale = __uint_as_float((unsigned)(262 - be) << 23); // 2^(135-be)
}

#if __has_builtin(__builtin_amdgcn_cvt_pk_fp8_f32) && __has_builtin(__builtin_amdgcn_cvt_pk_f32_fp8)
#define HAS_HW_FP8 1
#else
#define HAS_HW_FP8 0
#endif

#if !HAS_HW_FP8
// Fallback: exact bit-math e4m3 RNE (verified in round 0)
__device__ __forceinline__ float mx_e4m3(float x, float inv_scale, float scale) {
    float v  = x * inv_scale;
    float av = fabsf(v);
    int e = (int)(__float_as_uint(av) >> 23) - 127;
    e = e < -6 ? -6 : (e > 8 ? 8 : e);
    float qs = __uint_as_float((unsigned)(130 - e) << 23);
    float qm = __uint_as_float((unsigned)(124 + e) << 23);
    float q  = fminf(rintf(av * qs) * qm, 448.0f);
    return copysignf(q, v) * scale;
}
#endif

// Quantize 4 elems to e4m3 grid (RNE, saturate 448), return bf16 bits of value*scale.
__device__ __forceinline__ u16x4 quant4(float4 v, float inv, float sc) {
    u16x4 r;
#if HAS_HW_FP8
    float a = fminf(fmaxf(v.x * inv, -448.f), 448.f);
    float b = fminf(fmaxf(v.y * inv, -448.f), 448.f);
    float c = fminf(fmaxf(v.z * inv, -448.f), 448.f);
    float d = fminf(fmaxf(v.w * inv, -448.f), 448.f);
    int p = __builtin_amdgcn_cvt_pk_fp8_f32(a, b, 0, false);   // RNE f32->e4m3 (OCP)
    p     = __builtin_amdgcn_cvt_pk_fp8_f32(c, d, p, true);
    f32x2 lo = __builtin_amdgcn_cvt_pk_f32_fp8(p, false);      // exact e4m3->f32
    f32x2 hi = __builtin_amdgcn_cvt_pk_f32_fp8(p, true);
    r.x = (u16)(__float_as_uint(lo[0] * sc) >> 16);
    r.y = (u16)(__float_as_uint(lo[1] * sc) >> 16);
    r.z = (u16)(__float_as_uint(hi[0] * sc) >> 16);
    r.w = (u16)(__float_as_uint(hi[1] * sc) >> 16);
#else
    r.x = (u16)(__float_as_uint(mx_e4m3(v.x, inv, sc)) >> 16);
    r.y = (u16)(__float_as_uint(mx_e4m3(v.y, inv, sc)) >> 16);
    r.z = (u16)(__float_as_uint(mx_e4m3(v.z, inv, sc)) >> 16);
    r.w = (u16)(__float_as_uint(mx_e4m3(v.w, inv, sc)) >> 16);
#endif
    return r;
}

// Quantize 256x256 weight to bf16 fake-quant, stored TRANSPOSED: Bq[n*256+k].
__global__ void wq_kernel(const float* __restrict__ W, u16* __restrict__ Bq) {
    const int t  = blockIdx.x * blockDim.x + threadIdx.x;
    const int f  = t * 4;
    const int k  = f >> 8;
    const int n0 = f & 255;
    const float4 v = *(const float4*)(W + f);
    float am = fmaxf(fmaxf(fabsf(v.x), fabsf(v.y)), fmaxf(fabsf(v.z), fabsf(v.w)));
    am = fmaxf(am, __shfl_xor(am, 1));   // 8 lanes x 4 elems = one 32-elem MX block
    am = fmaxf(am, __shfl_xor(am, 2));
    am = fmaxf(am, __shfl_xor(am, 4));
    float sc, inv; block_scale(am, sc, inv);
    u16x4 q = quant4(v, inv, sc);
    Bq[(size_t)(n0 + 0) * 256 + k] = q.x;
    Bq[(size_t)(n0 + 1) * 256 + k] = q.y;
    Bq[(size_t)(n0 + 2) * 256 + k] = q.z;
    Bq[(size_t)(n0 + 3) * 256 + k] = q.w;
}

// R17 + zero-VGPR L2 prefetch of the next strip:
//  - per strip, AFTER issuing the 16 real float4 loads, each wave issues 16
//    global_load_lds ops for strip s+1's rows into a 1KB dummy LDS slot that is
//    NEVER read (all waves race into it -> harmless). vmcnt retires in order,
//    so quant's partial waits for real data never wait on the (newer) prefetch
//    ops. Effect: HBM streams strip s+1 into L2 during quant+MFMA(s); strip
//    s+1's real loads become L2 hits (~200cyc) -> HBM duty rises to ~continuous.
//  - everything else IDENTICAL to R17 (62.9 us, conflicts 786K, VGPR 96):
//    1 block (8 waves)/CU, whole B in fragment-native LDS layout, 4x128-row
//    strips, in-register quant, MFMA in four col-quarters, pacing s_barrier.
__global__ void __launch_bounds__(512, 1)
mx_gemm(const float* __restrict__ X, const u16* __restrict__ Bq,
        const float* __restrict__ bias, float* __restrict__ out)
{
    __shared__ u16   Bs[256 * 256];   // 128 KB: [ct][ks][slot] 1KB fragment tiles
    __shared__ float bs[256];         // bias
    __shared__ char  pfd[1024];       // dummy DMA sink (never read)
    const int tid = threadIdx.x;
    const int w   = tid >> 6;
    const int l   = tid & 63;
    const int lr  = l & 15;
    const int lg  = l >> 4;
    const size_t rowblk = (size_t)blockIdx.x * 512;

    // ---- one-time prologue: B -> LDS in fragment-native layout; bias -> LDS ----
    #pragma unroll
    for (int i = 0; i < 16; ++i) {
        const u32 g   = (u32)(tid + i * 512) * 16;     // linear byte offset in Bq
        const u32 n   = g >> 9;                        // output column 0..255
        const u32 kc  = (g >> 4) & 31;                 // ks*4 + lg
        const u32 ks  = kc >> 2;
        const u32 lgd = kc & 3;
        const u32 d   = (n >> 4) * 8192 + ks * 1024
                      + ((((lgd << 4) | (n & 15)) ^ (ks * 9)) << 4);
        *(bf16x8*)((char*)Bs + d) = *(const bf16x8*)((const char*)Bq + g);
    }
    if (tid < 256) bs[tid] = bias[tid];
    __syncthreads();

    const u32   lslot = (u32)(lg * 16 + lr);   // lane id: linear read pattern
    const char* BsB   = (const char*)Bs;

    #pragma unroll 1
    for (int s = 0; s < 4; ++s) {
        const size_t row0 = rowblk + (size_t)s * 128 + (size_t)w * 16;
        const float* xp = X + (row0 + lr) * 256 + lg * 8;

        // ---- 16 real strip loads, issued back-to-back ----
        float4 xv[16];
        #pragma unroll
        for (int kp = 0; kp < 8; ++kp) {
            xv[2 * kp]     = *(const float4*)(xp + kp * 32);
            xv[2 * kp + 1] = *(const float4*)(xp + kp * 32 + 4);
        }
        __builtin_amdgcn_sched_barrier(0);

        // ---- zero-VGPR prefetch: strip s+1 -> L2 (DMA to dummy LDS, no waits) ----
        if (s < 3) {
            const float* xn = X + (rowblk + (size_t)(s + 1) * 128 + (size_t)w * 16) * 256;
            #pragma unroll
            for (int r = 0; r < 16; ++r) {
                __builtin_amdgcn_global_load_lds(
                    (const __attribute__((address_space(1))) void*)(xn + r * 256 + l * 4),
                    (__attribute__((address_space(3))) void*)pfd, 16, 0, 0);
            }
        }
        __builtin_amdgcn_sched_barrier(0);

        // ---- quantize in-register: xv dies into af ----
        bf16x8 af[8];
        #pragma unroll
        for (int ks = 0; ks < 8; ++ks) {
            const float4 v0 = xv[2 * ks], v1 = xv[2 * ks + 1];
            float am = fmaxf(fmaxf(fabsf(v0.x), fabsf(v0.y)), fmaxf(fabsf(v0.z), fabsf(v0.w)));
            am = fmaxf(am, fmaxf(fmaxf(fabsf(v1.x), fabsf(v1.y)), fmaxf(fabsf(v1.z), fabsf(v1.w))));
            am = fmaxf(am, __shfl_xor(am, 16));   // other lg lanes, same row
            am = fmaxf(am, __shfl_xor(am, 32));   // = one 32-elem MX block per row
            float sc, inv; block_scale(am, sc, inv);
            const u16x4 q0 = quant4(v0, inv, sc);
            const u16x4 q1 = quant4(v1, inv, sc);
            bf16x8 a;
            a[0] = (short)q0.x; a[1] = (short)q0.y; a[2] = (short)q0.z; a[3] = (short)q0.w;
            a[4] = (short)q1.x; a[5] = (short)q1.y; a[6] = (short)q1.z; a[7] = (short)q1.w;
            af[ks] = a;
        }

        // ---- MFMA in four col-quarters (acc[4] live) vs LDS-resident B ----
        float* op = out + (row0 + lr) * 256 + lg * 4;
        #pragma unroll
        for (int h = 0; h < 4; ++h) {
            f32x4 acc[4];
            #pragma unroll
            for (int ct = 0; ct < 4; ++ct)
                acc[ct] = *(const f32x4*)(bs + (h * 4 + ct) * 16 + lg * 4);
            #pragma unroll
            for (int ks = 0; ks < 8; ++ks) {
                #pragma unroll
                for (int ct = 0; ct < 4; ++ct) {
                    const u32 off = (u32)(h * 4 + ct) * 8192 + (u32)ks * 1024
                                  + ((lslot ^ (u32)(ks * 9)) << 4);
                    const bf16x8 bf = *(const bf16x8*)(BsB + off);
                    acc[ct] = __builtin_amdgcn_mfma_f32_16x16x32_bf16(bf, af[ks], acc[ct], 0, 0, 0);
                }
            }
            #pragma unroll
            for (int ct = 0; ct < 4; ++ct)
                *(f32x4*)(op + (h * 4 + ct) * 16) = acc[ct];
        }

        // ---- pure pacing barrier: no waitcnt, loads/prefetch/stores in flight ----
        if (s < 3) __builtin_amdgcn_s_barrier();
    }
}

extern "C" void kernel_launch(void* const* d_in, const int* in_sizes, int n_in,
                              void* d_out, int out_size, void* d_ws, size_t ws_size,
                              hipStream_t stream) {
    const float* x    = (const float*)d_in[0];
    const float* wk   = (const float*)d_in[1];
    const float* bias = (const float*)d_in[2];
    float* out = (float*)d_out;
    u16* Bq    = (u16*)d_ws;                  // 256*256 bf16 = 128 KB scratch
    wq_kernel<<<64, 256, 0, stream>>>(wk, Bq);
    mx_gemm<<<NBLK, 512, 0, stream>>>(x, Bq, bias, out);
}

// Round 19
// 57.869 us; speedup vs baseline: 1.3559x; 1.3559x over previous
//
#include <hip/hip_runtime.h>
#include <hip/hip_bf16.h>

typedef unsigned short u16;
typedef unsigned int u32;
typedef __attribute__((ext_vector_type(8))) short bf16x8;
typedef __attribute__((ext_vector_type(4))) float f32x4;
typedef __attribute__((ext_vector_type(2))) float f32x2;
typedef __attribute__((ext_vector_type(4))) unsigned short u16x4;

#define NBLK 256   // 256 blocks x 512 rows = 131072 rows; 1 block/CU (LDS-capped)

// shared_exp = floor(log2(amax)) - 8 ; scale = 2^shared_exp (power of two)
__device__ __forceinline__ void block_scale(float amax, float& scale, float& inv_scale) {
    int be = (int)(__float_as_uint(amax) >> 23);   // biased exponent, amax >= 0
    be = be < 8 ? 8 : be;                          // tiny/zero blocks quantize to 0 anyway
    scale     = __uint_as_float((unsigned)(be - 8) << 23);   // 2^(be-135)
    inv_scale = __uint_as_float((unsigned)(262 - be) << 23); // 2^(135-be)
}

#if __has_builtin(__builtin_amdgcn_cvt_pk_fp8_f32) && __has_builtin(__builtin_amdgcn_cvt_pk_f32_fp8)
#define HAS_HW_FP8 1
#else
#define HAS_HW_FP8 0
#endif

#if !HAS_HW_FP8
// Fallback: exact bit-math e4m3 RNE (verified in round 0)
__device__ __forceinline__ float mx_e4m3(float x, float inv_scale, float scale) {
    float v  = x * inv_scale;
    float av = fabsf(v);
    int e = (int)(__float_as_uint(av) >> 23) - 127;
    e = e < -6 ? -6 : (e > 8 ? 8 : e);
    float qs = __uint_as_float((unsigned)(130 - e) << 23);
    float qm = __uint_as_float((unsigned)(124 + e) << 23);
    float q  = fminf(rintf(av * qs) * qm, 448.0f);
    return copysignf(q, v) * scale;
}
#endif

// Quantize 4 elems to e4m3 grid (RNE, saturate 448), return bf16 bits of value*scale.
__device__ __forceinline__ u16x4 quant4(float4 v, float inv, float sc) {
    u16x4 r;
#if HAS_HW_FP8
    float a = fminf(fmaxf(v.x * inv, -448.f), 448.f);
    float b = fminf(fmaxf(v.y * inv, -448.f), 448.f);
    float c = fminf(fmaxf(v.z * inv, -448.f), 448.f);
    float d = fminf(fmaxf(v.w * inv, -448.f), 448.f);
    int p = __builtin_amdgcn_cvt_pk_fp8_f32(a, b, 0, false);   // RNE f32->e4m3 (OCP)
    p     = __builtin_amdgcn_cvt_pk_fp8_f32(c, d, p, true);
    f32x2 lo = __builtin_amdgcn_cvt_pk_f32_fp8(p, false);      // exact e4m3->f32
    f32x2 hi = __builtin_amdgcn_cvt_pk_f32_fp8(p, true);
    r.x = (u16)(__float_as_uint(lo[0] * sc) >> 16);
    r.y = (u16)(__float_as_uint(lo[1] * sc) >> 16);
    r.z = (u16)(__float_as_uint(hi[0] * sc) >> 16);
    r.w = (u16)(__float_as_uint(hi[1] * sc) >> 16);
#else
    r.x = (u16)(__float_as_uint(mx_e4m3(v.x, inv, sc)) >> 16);
    r.y = (u16)(__float_as_uint(mx_e4m3(v.y, inv, sc)) >> 16);
    r.z = (u16)(__float_as_uint(mx_e4m3(v.z, inv, sc)) >> 16);
    r.w = (u16)(__float_as_uint(mx_e4m3(v.w, inv, sc)) >> 16);
#endif
    return r;
}

// Quantize 256x256 weight to bf16 fake-quant, stored TRANSPOSED: Bq[n*256+k].
__global__ void wq_kernel(const float* __restrict__ W, u16* __restrict__ Bq) {
    const int t  = blockIdx.x * blockDim.x + threadIdx.x;
    const int f  = t * 4;
    const int k  = f >> 8;
    const int n0 = f & 255;
    const float4 v = *(const float4*)(W + f);
    float am = fmaxf(fmaxf(fabsf(v.x), fabsf(v.y)), fmaxf(fabsf(v.z), fabsf(v.w)));
    am = fmaxf(am, __shfl_xor(am, 1));   // 8 lanes x 4 elems = one 32-elem MX block
    am = fmaxf(am, __shfl_xor(am, 2));
    am = fmaxf(am, __shfl_xor(am, 4));
    float sc, inv; block_scale(am, sc, inv);
    u16x4 q = quant4(v, inv, sc);
    Bq[(size_t)(n0 + 0) * 256 + k] = q.x;
    Bq[(size_t)(n0 + 1) * 256 + k] = q.y;
    Bq[(size_t)(n0 + 2) * 256 + k] = q.z;
    Bq[(size_t)(n0 + 3) * 256 + k] = q.w;
}

// R17 with halved B-LDS traffic: 32 rows per wave per B-sweep.
//  - 2 strips x 256 rows; per strip each wave quantizes TWO 16-row tiles
//    (af0: rows w*16+lr, af1: rows 128+w*16+lr), xv registers reused serially
//    so peaks stay ~110 VGPR (af 64 + xv 64 never co-live with acc 32).
//  - each B-fragment ds_read now feeds 2 MFMA (one per row-tile): per-CU LDS
//    read traffic halves (4MB -> 2MB), serial strip boundaries halve (4 -> 2).
//  - B LDS layout, quant math, fragment mapping, pacing barrier, traffic
//    discipline all identical to R17 (62.9 us verified).
__global__ void __launch_bounds__(512, 1)
mx_gemm(const float* __restrict__ X, const u16* __restrict__ Bq,
        const float* __restrict__ bias, float* __restrict__ out)
{
    __shared__ u16   Bs[256 * 256];   // 128 KB: [ct][ks][slot] 1KB fragment tiles
    __shared__ float bs[256];         // bias
    const int tid = threadIdx.x;
    const int w   = tid >> 6;
    const int l   = tid & 63;
    const int lr  = l & 15;
    const int lg  = l >> 4;
    const size_t rowblk = (size_t)blockIdx.x * 512;

    // ---- one-time prologue: B -> LDS in fragment-native layout; bias -> LDS ----
    #pragma unroll
    for (int i = 0; i < 16; ++i) {
        const u32 g   = (u32)(tid + i * 512) * 16;     // linear byte offset in Bq
        const u32 n   = g >> 9;                        // output column 0..255
        const u32 kc  = (g >> 4) & 31;                 // ks*4 + lg
        const u32 ks  = kc >> 2;
        const u32 lgd = kc & 3;
        const u32 d   = (n >> 4) * 8192 + ks * 1024
                      + ((((lgd << 4) | (n & 15)) ^ (ks * 9)) << 4);
        *(bf16x8*)((char*)Bs + d) = *(const bf16x8*)((const char*)Bq + g);
    }
    if (tid < 256) bs[tid] = bias[tid];
    __syncthreads();

    const u32   lslot = (u32)(lg * 16 + lr);   // lane id: linear read pattern
    const char* BsB   = (const char*)Bs;

    #pragma unroll 1
    for (int s = 0; s < 2; ++s) {
        const size_t rowt0 = rowblk + (size_t)s * 256 + (size_t)w * 16;  // tile 0
        // tile 1 = rowt0 + 128

        bf16x8 af0[8], af1[8];
        #pragma unroll
        for (int half = 0; half < 2; ++half) {
            const float* xp = X + (rowt0 + (size_t)half * 128 + lr) * 256 + lg * 8;
            // ---- 16 tile loads, issued back-to-back ----
            float4 xv[16];
            #pragma unroll
            for (int kp = 0; kp < 8; ++kp) {
                xv[2 * kp]     = *(const float4*)(xp + kp * 32);
                xv[2 * kp + 1] = *(const float4*)(xp + kp * 32 + 4);
            }
            // ---- quantize in-register: xv dies into af ----
            #pragma unroll
            for (int ks = 0; ks < 8; ++ks) {
                const float4 v0 = xv[2 * ks], v1 = xv[2 * ks + 1];
                float am = fmaxf(fmaxf(fabsf(v0.x), fabsf(v0.y)), fmaxf(fabsf(v0.z), fabsf(v0.w)));
                am = fmaxf(am, fmaxf(fmaxf(fabsf(v1.x), fabsf(v1.y)), fmaxf(fabsf(v1.z), fabsf(v1.w))));
                am = fmaxf(am, __shfl_xor(am, 16));   // other lg lanes, same row
                am = fmaxf(am, __shfl_xor(am, 32));   // = one 32-elem MX block per row
                float sc, inv; block_scale(am, sc, inv);
                const u16x4 q0 = quant4(v0, inv, sc);
                const u16x4 q1 = quant4(v1, inv, sc);
                bf16x8 a;
                a[0] = (short)q0.x; a[1] = (short)q0.y; a[2] = (short)q0.z; a[3] = (short)q0.w;
                a[4] = (short)q1.x; a[5] = (short)q1.y; a[6] = (short)q1.z; a[7] = (short)q1.w;
                if (half == 0) af0[ks] = a; else af1[ks] = a;
            }
        }

        // ---- MFMA in four col-quarters; each B ds_read feeds BOTH row-tiles ----
        float* op0 = out + (rowt0 + lr) * 256 + lg * 4;
        float* op1 = op0 + (size_t)128 * 256;
        #pragma unroll
        for (int h = 0; h < 4; ++h) {
            f32x4 acc0[4], acc1[4];
            #pragma unroll
            for (int ct = 0; ct < 4; ++ct) {
                const f32x4 bv = *(const f32x4*)(bs + (h * 4 + ct) * 16 + lg * 4);
                acc0[ct] = bv; acc1[ct] = bv;
            }
            #pragma unroll
            for (int ks = 0; ks < 8; ++ks) {
                #pragma unroll
                for (int ct = 0; ct < 4; ++ct) {
                    const u32 off = (u32)(h * 4 + ct) * 8192 + (u32)ks * 1024
                                  + ((lslot ^ (u32)(ks * 9)) << 4);
                    const bf16x8 bf = *(const bf16x8*)(BsB + off);
                    acc0[ct] = __builtin_amdgcn_mfma_f32_16x16x32_bf16(bf, af0[ks], acc0[ct], 0, 0, 0);
                    acc1[ct] = __builtin_amdgcn_mfma_f32_16x16x32_bf16(bf, af1[ks], acc1[ct], 0, 0, 0);
                }
            }
            #pragma unroll
            for (int ct = 0; ct < 4; ++ct) {
                *(f32x4*)(op0 + (h * 4 + ct) * 16) = acc0[ct];
                *(f32x4*)(op1 + (h * 4 + ct) * 16) = acc1[ct];
            }
        }

        // ---- pure pacing barrier: no waitcnt, loads/stores stay in flight ----
        if (s < 1) __builtin_amdgcn_s_barrier();
    }
}

extern "C" void kernel_launch(void* const* d_in, const int* in_sizes, int n_in,
                              void* d_out, int out_size, void* d_ws, size_t ws_size,
                              hipStream_t stream) {
    const float* x    = (const float*)d_in[0];
    const float* wk   = (const float*)d_in[1];
    const float* bias = (const float*)d_in[2];
    float* out = (float*)d_out;
    u16* Bq    = (u16*)d_ws;                  // 256*256 bf16 = 128 KB scratch
    wq_kernel<<<64, 256, 0, stream>>>(wk, Bq);
    mx_gemm<<<NBLK, 512, 0, stream>>>(x, Bq, bias, out);
}